// Round 15
// baseline (25051.030 us; speedup 1.0000x reference)
//
#include <hip/hip_runtime.h>
#include <hip/hip_fp16.h>
#include <cstdint>

#define B_SZ 4
#define T_SZ 512
#define D_SZ 768
#define H_SZ 768
#define G4   3072           // 4*H
#define V_SZ 50257
#define V_PAD 50304         // 393*128
#define M_SZ 2048           // T*B
#define FUSE_WGS 192        // 96 L0 blocks + 96 L1 blocks, 256 threads each

using half8 = __attribute__((ext_vector_type(8))) _Float16;
using half2v = __attribute__((ext_vector_type(2))) _Float16;
using f32x4 = __attribute__((ext_vector_type(4))) float;
typedef unsigned long long ull;

// ---------------- conversion kernels ----------------

__global__ void conv_A0(const float* __restrict__ reps, _Float16* __restrict__ A0) {
  int idx = blockIdx.x * blockDim.x + threadIdx.x;
  const int total = M_SZ * D_SZ;
  for (; idx < total; idx += gridDim.x * blockDim.x) {
    int k = idx % D_SZ, m = idx / D_SZ;
    int t = m >> 2, b = m & 3;
    A0[idx] = (_Float16)reps[(b * T_SZ + t) * D_SZ + k];
  }
}

__global__ void conv_cast(const float* __restrict__ src, _Float16* __restrict__ dst, int n) {
  int idx = blockIdx.x * blockDim.x + threadIdx.x;
  for (; idx < n; idx += gridDim.x * blockDim.x) dst[idx] = (_Float16)src[idx];
}

__global__ void conv_head(const float* __restrict__ w, _Float16* __restrict__ dst) {
  int idx = blockIdx.x * blockDim.x + threadIdx.x;
  const int total = V_PAD * H_SZ;
  for (; idx < total; idx += gridDim.x * blockDim.x) {
    int n = idx / H_SZ, k = idx % H_SZ;
    dst[idx] = (n < V_SZ) ? (_Float16)w[n * H_SZ + k] : (_Float16)0.f;
  }
}

// ---------------- f16 MFMA GEMM: C[m][n] = sum_k A[m][k]*B[n][k] + bias[n] ----------------

__global__ __launch_bounds__(256) void gemm_bt_f16(
    const _Float16* __restrict__ A, const _Float16* __restrict__ B,
    const float* __restrict__ bias, float* __restrict__ C,
    int M, int N, int K, int mode, int Nreal)
{
  __shared__ __align__(16) _Float16 As[128][32];
  __shared__ __align__(16) _Float16 Bs[128][32];
  const int t = threadIdx.x;
  const int lane = t & 63, w = t >> 6;
  const int wr = w >> 1, wc = w & 1;
  const int m0 = blockIdx.x * 128, n0 = blockIdx.y * 128;

  f32x4 acc[4][4] = {};

  const int srow = t >> 2;
  const int scol = (t & 3) * 8;

  for (int k0 = 0; k0 < K; k0 += 32) {
    uint4 av0 = *(const uint4*)&A[(size_t)(m0 + srow) * K + k0 + scol];
    uint4 av1 = *(const uint4*)&A[(size_t)(m0 + 64 + srow) * K + k0 + scol];
    uint4 bv0 = *(const uint4*)&B[(size_t)(n0 + srow) * K + k0 + scol];
    uint4 bv1 = *(const uint4*)&B[(size_t)(n0 + 64 + srow) * K + k0 + scol];
    __syncthreads();
    *(uint4*)&As[srow][scol]      = av0;
    *(uint4*)&As[64 + srow][scol] = av1;
    *(uint4*)&Bs[srow][scol]      = bv0;
    *(uint4*)&Bs[64 + srow][scol] = bv1;
    __syncthreads();

    const int fr = lane & 15, k8 = (lane >> 4) * 8;
    half8 af[4], bf[4];
#pragma unroll
    for (int i = 0; i < 4; ++i) {
      af[i] = *(const half8*)&As[wr * 64 + i * 16 + fr][k8];
      bf[i] = *(const half8*)&Bs[wc * 64 + i * 16 + fr][k8];
    }
#pragma unroll
    for (int i = 0; i < 4; ++i)
#pragma unroll
      for (int j = 0; j < 4; ++j)
        acc[i][j] = __builtin_amdgcn_mfma_f32_16x16x32_f16(af[i], bf[j], acc[i][j], 0, 0, 0);
  }

  const int fr = lane & 15, rq = lane >> 4;
#pragma unroll
  for (int i = 0; i < 4; ++i) {
#pragma unroll
    for (int j = 0; j < 4; ++j) {
      int n = n0 + wc * 64 + j * 16 + fr;
      if (n >= Nreal) continue;
      float bv = bias[n];
#pragma unroll
      for (int r = 0; r < 4; ++r) {
        int m = m0 + wr * 64 + i * 16 + rq * 4 + r;
        float v = acc[i][j][r] + bv;
        if (mode == 0) {
          C[(size_t)m * N + n] = v;
        } else {
          int tt = m >> 2, bb = m & 3;
          C[(size_t)(bb * T_SZ + tt) * V_SZ + n] = v;
        }
      }
    }
  }
}

// ---------------- round-15 scan: r13 structure + early-compression butterfly ----------------
// r13/r14 PASSED but spilled (VGPR 256, GB-scale scratch). r12 (248, no spill)
// differs in ONE register-shape property: its 32 acc scalars die after 4
// butterfly rounds (LDS dump). r13/r14 kept them live through 6 rounds + the
// combine -> allocator spilled hot weights. THE FIX: after masks 1..8
// (identical to r12), every lane SELECTS the 4 scalars destined for its own
// (col,b) slot -- component bl=lane&3 of acc[g][c2l=(lane>>2)&1] -- then only
// those 4 run masks 16/32 (8 shfl). Selection is butterfly-consistent:
// partners under masks 16/32 share low-4 lane bits. acc dies at selection,
// matching r12's proven liveness, minus 48 regs (wreg2 fp16, r14-proven).
// All sync logic is r13's (two passes proved it correct):
//   ring[8] of [tag|f32] 8B words both layers; reader epoch x: slot (x-1)&7
//   tag >= x; L1 seeds slot 0 tag 1 at e=0 (continue, no LDS); L0 back-
//   pressure e>=5: one h1 word slot (e-5)&7 tag >= e-4 (caps lead < 8);
//   ONE __syncthreads per epoch; LDS h-staging double-buffered (parity e&1).

__global__ __launch_bounds__(256) void lstm_fused(
    const float* __restrict__ xg0,    // (2048,3072) layer-0 input projections
    const float* __restrict__ Wih1,   // (3072,768) fp32 layer-1 input weights
    const float* __restrict__ Whh,    // (2,3072,768) fp32
    const float* __restrict__ bias,   // (2,3072) fp32
    ull* __restrict__ hx0p,           // [8][3072] packed ring, pre-zeroed
    ull* __restrict__ hx1p,           // [8][3072] packed ring, pre-zeroed
    _Float16* __restrict__ h1hist)    // (2048,768) fp16, row = t*4+b
{
  __shared__ __align__(16) float h0buf[2][G4];
  __shared__ __align__(16) float h1buf[2][G4];

  const int t = threadIdx.x, lane = t & 63, wv = t >> 6;
  const bool L1 = blockIdx.x >= 96;
  const int lid = L1 ? (blockIdx.x - 96) : blockIdx.x;
  const int j0 = lid * 8;
  const int col0 = j0 + wv * 2;

  const float* WhhL = Whh + (L1 ? (size_t)G4 * H_SZ : 0);

  // W_hh fp32: wreg[g][c2][kk] = W[row = g*768 + col0+c2][k = kk*64 + lane]
  float wreg[4][2][12];
#pragma unroll
  for (int g = 0; g < 4; ++g)
#pragma unroll
    for (int c2 = 0; c2 < 2; ++c2)
#pragma unroll
      for (int kk = 0; kk < 12; ++kk)
        wreg[g][c2][kk] = WhhL[(size_t)(g * H_SZ + col0 + c2) * H_SZ + kk * 64 + lane];

  // W_ih1 fp16-packed: wreg2h[g][c2][j] = (kk=2j, kk=2j+1)
  half2v wreg2h[4][2][6];
  if (L1) {
#pragma unroll
    for (int g = 0; g < 4; ++g)
#pragma unroll
      for (int c2 = 0; c2 < 2; ++c2)
#pragma unroll
        for (int j = 0; j < 6; ++j) {
          half2v p;
          p.x = (_Float16)Wih1[(size_t)(g * H_SZ + col0 + c2) * H_SZ + (2 * j) * 64 + lane];
          p.y = (_Float16)Wih1[(size_t)(g * H_SZ + col0 + c2) * H_SZ + (2 * j + 1) * 64 + lane];
          wreg2h[g][c2][j] = p;
        }
  }

  // combine-lane mapping: c2 = (lane>>2)&1, b = lane&3 (consistent across
  // shfl partners at masks 16/32 since low-4 bits match)
  const int c2l = (lane >> 2) & 1, bl = lane & 3;
  const int mycol = col0 + c2l;
  float cstate = 0.f;
  float bias4[4] = {0.f, 0.f, 0.f, 0.f};
  if (L1 && lane < 8) {
#pragma unroll
    for (int g = 0; g < 4; ++g) bias4[g] = bias[G4 + g * H_SZ + mycol];
  }

  const int elim = L1 ? 513 : 512;
  for (int e = 0; e < elim; ++e) {
    if (L1 && e == 0) {
      if (t < 32) {
        int c = t >> 2, b = t & 3;
        __hip_atomic_store(&hx1p[(size_t)(j0 + c) * 4 + b], (ull)1u << 32,
                           __ATOMIC_RELAXED, __HIP_MEMORY_SCOPE_AGENT);
      }
      continue;  // block-uniform: no LDS touched, barrier legally skipped
    }

    // back-pressure (L0, t0, e>=5): one h1 word, slot (e-5)&7, tag >= e-4
    if (!L1 && t == 0 && e >= 5) {
      const ull* bp = hx1p + (size_t)((e - 5) & 7) * G4;
      while ((unsigned)(__hip_atomic_load(bp, __ATOMIC_RELAXED, __HIP_MEMORY_SCOPE_AGENT) >> 32)
             < (unsigned)(e - 4))
        __builtin_amdgcn_s_sleep(1);
    }

    const unsigned need = (unsigned)e;
    const int sbuf = e & 1;

    // gather h0[e-1] (ring slot (e-1)&7), tag-poll, stage to LDS -- 2x6 words
    {
      const ull* s0 = hx0p + (size_t)((e + 7) & 7) * G4;
#pragma unroll
      for (int hf = 0; hf < 2; ++hf) {
        ull v[6];
#pragma unroll
        for (int i = 0; i < 6; ++i)
          v[i] = __hip_atomic_load(&s0[t + (hf * 6 + i) * 256], __ATOMIC_RELAXED, __HIP_MEMORY_SCOPE_AGENT);
        for (;;) {
          bool stale = false;
#pragma unroll
          for (int i = 0; i < 6; ++i) stale |= ((unsigned)(v[i] >> 32) < need);
          if (!stale) break;
          __builtin_amdgcn_s_sleep(1);
#pragma unroll
          for (int i = 0; i < 6; ++i)
            if ((unsigned)(v[i] >> 32) < need)
              v[i] = __hip_atomic_load(&s0[t + (hf * 6 + i) * 256], __ATOMIC_RELAXED, __HIP_MEMORY_SCOPE_AGENT);
        }
#pragma unroll
        for (int i = 0; i < 6; ++i)
          h0buf[sbuf][t + (hf * 6 + i) * 256] = __uint_as_float((unsigned)v[i]);
      }
    }
    // L1: gather h1[e-2]-carry (ring slot (e-1)&7) -- 2x6 words
    if (L1) {
      const ull* s1 = hx1p + (size_t)((e + 7) & 7) * G4;
#pragma unroll
      for (int hf = 0; hf < 2; ++hf) {
        ull v[6];
#pragma unroll
        for (int i = 0; i < 6; ++i)
          v[i] = __hip_atomic_load(&s1[t + (hf * 6 + i) * 256], __ATOMIC_RELAXED, __HIP_MEMORY_SCOPE_AGENT);
        for (;;) {
          bool stale = false;
#pragma unroll
          for (int i = 0; i < 6; ++i) stale |= ((unsigned)(v[i] >> 32) < need);
          if (!stale) break;
          __builtin_amdgcn_s_sleep(1);
#pragma unroll
          for (int i = 0; i < 6; ++i)
            if ((unsigned)(v[i] >> 32) < need)
              v[i] = __hip_atomic_load(&s1[t + (hf * 6 + i) * 256], __ATOMIC_RELAXED, __HIP_MEMORY_SCOPE_AGENT);
        }
#pragma unroll
        for (int i = 0; i < 6; ++i)
          h1buf[sbuf][t + (hf * 6 + i) * 256] = __uint_as_float((unsigned)v[i]);
      }
    }
    __syncthreads();   // the single per-epoch barrier

    // matvec: lane covers k-slice {lane + 64*kk}
    f32x4 acc[4][2] = {};
    if (!L1) {
#pragma unroll
      for (int kk = 0; kk < 12; ++kk) {
        f32x4 x4 = *(const f32x4*)&h0buf[sbuf][(kk * 64 + lane) * 4];
#pragma unroll
        for (int g = 0; g < 4; ++g)
#pragma unroll
          for (int c2 = 0; c2 < 2; ++c2)
            acc[g][c2] += wreg[g][c2][kk] * x4;
      }
    } else {
#pragma unroll
      for (int kk = 0; kk < 12; ++kk) {
        f32x4 x4 = *(const f32x4*)&h0buf[sbuf][(kk * 64 + lane) * 4];
        f32x4 h4 = *(const f32x4*)&h1buf[sbuf][(kk * 64 + lane) * 4];
#pragma unroll
        for (int g = 0; g < 4; ++g)
#pragma unroll
          for (int c2 = 0; c2 < 2; ++c2) {
            half2v p = wreg2h[g][c2][kk >> 1];
            float wx = (float)((kk & 1) ? p.y : p.x);   // static at unroll
            acc[g][c2] += wx * x4 + wreg[g][c2][kk] * h4;
          }
      }
    }

    // butterfly stage 1 (r12-identical): masks 1..8 within 16-lane groups
#pragma unroll
    for (int mask = 1; mask <= 8; mask <<= 1) {
#pragma unroll
      for (int g = 0; g < 4; ++g)
#pragma unroll
        for (int c2 = 0; c2 < 2; ++c2) {
          acc[g][c2].x += __shfl_xor(acc[g][c2].x, mask, 64);
          acc[g][c2].y += __shfl_xor(acc[g][c2].y, mask, 64);
          acc[g][c2].z += __shfl_xor(acc[g][c2].z, mask, 64);
          acc[g][c2].w += __shfl_xor(acc[g][c2].w, mask, 64);
        }
    }

    // EARLY COMPRESSION: each lane keeps only its (c2l, bl) scalars; the
    // 32-wide acc dies HERE (r12's liveness shape). Then masks 16/32 on 4.
    float s4[4];
#pragma unroll
    for (int g = 0; g < 4; ++g) {
      f32x4 ag = c2l ? acc[g][1] : acc[g][0];
      s4[g] = (bl == 0) ? ag.x : (bl == 1) ? ag.y : (bl == 2) ? ag.z : ag.w;
    }
#pragma unroll
    for (int g = 0; g < 4; ++g) {
      s4[g] += __shfl_xor(s4[g], 16, 64);
      s4[g] += __shfl_xor(s4[g], 32, 64);
    }

    // in-wave combine: lanes 0..7 finish (c2l, bl) of this wave's 2 cols
    if (lane < 8) {
      if (L1) {
#pragma unroll
        for (int g = 0; g < 4; ++g) s4[g] += bias4[g];
      } else {
        const float* xp = xg0 + (size_t)((e << 2) + bl) * G4 + mycol;
#pragma unroll
        for (int g = 0; g < 4; ++g) s4[g] += xp[g * H_SZ];  // L0 slack hides latency
      }
      float iv = 1.f / (1.f + expf(-s4[0]));
      float fv = 1.f / (1.f + expf(-s4[1]));
      float gv = tanhf(s4[2]);
      float ov = 1.f / (1.f + expf(-s4[3]));
      cstate = fv * cstate + iv * gv;
      float hn = ov * tanhf(cstate);
      ull p = ((ull)(unsigned)(e + 1) << 32) | (ull)__float_as_uint(hn);
      ull* dst = (L1 ? hx1p : hx0p) + (size_t)(e & 7) * G4;
      __hip_atomic_store(&dst[(size_t)mycol * 4 + bl], p,
                         __ATOMIC_RELAXED, __HIP_MEMORY_SCOPE_AGENT);
      if (L1)
        h1hist[(size_t)(((e - 1) << 2) + bl) * H_SZ + mycol] = (_Float16)hn;
    }
  }
}

// ---------------- launcher ----------------

extern "C" void kernel_launch(void* const* d_in, const int* in_sizes, int n_in,
                              void* d_out, int out_size, void* d_ws, size_t ws_size,
                              hipStream_t stream) {
  const float* reps   = (const float*)d_in[0];
  const float* W_ih   = (const float*)d_in[1];
  const float* W_hh   = (const float*)d_in[2];
  const float* bias   = (const float*)d_in[3];
  const float* head_w = (const float*)d_in[4];
  const float* head_b = (const float*)d_in[5];
  float* out = (float*)d_out;

  char* ws = (char*)d_ws;
  _Float16* A0h    = (_Float16*)(ws + 0);            //  3,145,728 B
  _Float16* Wih_h  = (_Float16*)(ws + 3145728);      //  4,718,592 B (layer 0 only)
  _Float16* Whead  = (_Float16*)(ws + 12582912);     // 77,266,944 B (padded)
  float*    xg0    = (float*)   (ws + 89849856);     // 25,165,824 B
  _Float16* h1hist = (_Float16*)(ws + 115015680);    //  3,145,728 B
  ull*      hx0p   = (ull*)     (ws + 118161408);    //    196,608 B ([8][3072] packed)
  ull*      hx1p   = (ull*)     (ws + 118358016);    //    196,608 B ([8][3072] packed)

  // conversions
  hipLaunchKernelGGL(conv_A0,   dim3(1024), dim3(256), 0, stream, reps, A0h);
  hipLaunchKernelGGL(conv_cast, dim3(1024), dim3(256), 0, stream, W_ih, Wih_h, G4 * D_SZ);
  hipLaunchKernelGGL(conv_head, dim3(4096), dim3(256), 0, stream, head_w, Whead);

  // xg0 = A0 * Wih0^T + b0
  hipLaunchKernelGGL(gemm_bt_f16, dim3(16, 24), dim3(256), 0, stream,
                     A0h, Wih_h, bias, xg0, M_SZ, G4, H_SZ, 0, G4);

  // ring-tag pipelined 2-layer scan (192 blocks x 256 threads)
  hipMemsetAsync(hx0p, 0, 393216, stream);  // hx0p + hx1p contiguous
  hipLaunchKernelGGL(lstm_fused, dim3(FUSE_WGS), dim3(256), 0, stream,
                     xg0, W_ih + (size_t)G4 * D_SZ, W_hh, bias,
                     hx0p, hx1p, h1hist);

  // logits = h1 * head_w^T + head_b  (padded N, permuted store into (B,T,V))
  hipLaunchKernelGGL(gemm_bt_f16, dim3(16, 393), dim3(256), 0, stream,
                     h1hist, Whead, head_b, out, M_SZ, V_PAD, H_SZ, 1, V_SZ);
}

// Round 16
// 3016.613 us; speedup vs baseline: 8.3044x; 8.3044x over previous
//
#include <hip/hip_runtime.h>
#include <hip/hip_fp16.h>
#include <cstdint>

#define B_SZ 4
#define T_SZ 512
#define D_SZ 768
#define H_SZ 768
#define G4   3072           // 4*H
#define V_SZ 50257
#define V_PAD 50304         // 393*128
#define M_SZ 2048           // T*B
#define FUSE_WGS 192        // 96 L0 blocks + 96 L1 blocks, 256 threads each

using half8 = __attribute__((ext_vector_type(8))) _Float16;
using f32x4 = __attribute__((ext_vector_type(4))) float;
typedef unsigned long long ull;

// ---------------- conversion kernels ----------------

__global__ void conv_A0(const float* __restrict__ reps, _Float16* __restrict__ A0) {
  int idx = blockIdx.x * blockDim.x + threadIdx.x;
  const int total = M_SZ * D_SZ;
  for (; idx < total; idx += gridDim.x * blockDim.x) {
    int k = idx % D_SZ, m = idx / D_SZ;
    int t = m >> 2, b = m & 3;
    A0[idx] = (_Float16)reps[(b * T_SZ + t) * D_SZ + k];
  }
}

__global__ void conv_cast(const float* __restrict__ src, _Float16* __restrict__ dst, int n) {
  int idx = blockIdx.x * blockDim.x + threadIdx.x;
  for (; idx < n; idx += gridDim.x * blockDim.x) dst[idx] = (_Float16)src[idx];
}

__global__ void conv_head(const float* __restrict__ w, _Float16* __restrict__ dst) {
  int idx = blockIdx.x * blockDim.x + threadIdx.x;
  const int total = V_PAD * H_SZ;
  for (; idx < total; idx += gridDim.x * blockDim.x) {
    int n = idx / H_SZ, k = idx % H_SZ;
    dst[idx] = (n < V_SZ) ? (_Float16)w[n * H_SZ + k] : (_Float16)0.f;
  }
}

// ---------------- f16 MFMA GEMM: C[m][n] = sum_k A[m][k]*B[n][k] + bias[n] ----------------

__global__ __launch_bounds__(256) void gemm_bt_f16(
    const _Float16* __restrict__ A, const _Float16* __restrict__ B,
    const float* __restrict__ bias, float* __restrict__ C,
    int M, int N, int K, int mode, int Nreal)
{
  __shared__ __align__(16) _Float16 As[128][32];
  __shared__ __align__(16) _Float16 Bs[128][32];
  const int t = threadIdx.x;
  const int lane = t & 63, w = t >> 6;
  const int wr = w >> 1, wc = w & 1;
  const int m0 = blockIdx.x * 128, n0 = blockIdx.y * 128;

  f32x4 acc[4][4] = {};

  const int srow = t >> 2;
  const int scol = (t & 3) * 8;

  for (int k0 = 0; k0 < K; k0 += 32) {
    uint4 av0 = *(const uint4*)&A[(size_t)(m0 + srow) * K + k0 + scol];
    uint4 av1 = *(const uint4*)&A[(size_t)(m0 + 64 + srow) * K + k0 + scol];
    uint4 bv0 = *(const uint4*)&B[(size_t)(n0 + srow) * K + k0 + scol];
    uint4 bv1 = *(const uint4*)&B[(size_t)(n0 + 64 + srow) * K + k0 + scol];
    __syncthreads();
    *(uint4*)&As[srow][scol]      = av0;
    *(uint4*)&As[64 + srow][scol] = av1;
    *(uint4*)&Bs[srow][scol]      = bv0;
    *(uint4*)&Bs[64 + srow][scol] = bv1;
    __syncthreads();

    const int fr = lane & 15, k8 = (lane >> 4) * 8;
    half8 af[4], bf[4];
#pragma unroll
    for (int i = 0; i < 4; ++i) {
      af[i] = *(const half8*)&As[wr * 64 + i * 16 + fr][k8];
      bf[i] = *(const half8*)&Bs[wc * 64 + i * 16 + fr][k8];
    }
#pragma unroll
    for (int i = 0; i < 4; ++i)
#pragma unroll
      for (int j = 0; j < 4; ++j)
        acc[i][j] = __builtin_amdgcn_mfma_f32_16x16x32_f16(af[i], bf[j], acc[i][j], 0, 0, 0);
  }

  const int fr = lane & 15, rq = lane >> 4;
#pragma unroll
  for (int i = 0; i < 4; ++i) {
#pragma unroll
    for (int j = 0; j < 4; ++j) {
      int n = n0 + wc * 64 + j * 16 + fr;
      if (n >= Nreal) continue;
      float bv = bias[n];
#pragma unroll
      for (int r = 0; r < 4; ++r) {
        int m = m0 + wr * 64 + i * 16 + rq * 4 + r;
        float v = acc[i][j][r] + bv;
        if (mode == 0) {
          C[(size_t)m * N + n] = v;
        } else {
          int tt = m >> 2, bb = m & 3;
          C[(size_t)(bb * T_SZ + tt) * V_SZ + n] = v;
        }
      }
    }
  }
}

// ---------------- round-16 scan: r12 COMPUTE + r13 SYNC ----------------
// r13/14/15 compute-restructure all spilled (VGPR 256, GB scratch) despite
// correct logic (3 passes). Revert to r12's compute shape (proven 248 VGPR,
// no spill): wave = 1 gate x 8 cols, masks 1..8 butterfly, red[] LDS dump,
// t<128 activation, t<32 combine, 3 syncs. Port r13's PROVEN sync design:
//  - h0/h1 both ring[8] of [tag:u32|f32:u32] 8B relaxed agent atomics.
//    Store at epoch e -> slot e&7 tag e+1; reader epoch x -> slot (x-1)&7
//    tag >= x. Tag IS the sync (r12-proven one-hop).
//  - NO FLAGS, NO vmcnt drain (r12's vmcnt+flag guarded reads only; tags
//    carry data-visibility; read-guards need no store drain). Wave 0's
//    ~0.5-1us MALL-ack wait per epoch is gone.
//  - intra-group anti-dep: free via tag transitivity (mutual lag <= 1).
//  - cross-group: L0 t0 back-pressure at e>=5 polls ONE h1 word, slot
//    (e-5)&7 tag >= e-4 => all L1 >= epoch e-6 => h0[e-8] reads done
//    (r13-proven transitive argument); caps L0 lead < 8.
//  - L1 e=0: seed h1 ring slot 0 (tag 1, zeros = h1[-1]) then uniform
//    continue (no LDS touched, barrier legally skipped).

__global__ __launch_bounds__(256) void lstm_fused(
    const float* __restrict__ xg0,    // (2048,3072) layer-0 input projections
    const float* __restrict__ Wih1,   // (3072,768) fp32 layer-1 input weights
    const float* __restrict__ Whh,    // (2,3072,768) fp32
    const float* __restrict__ bias,   // (2,3072) fp32
    ull* __restrict__ hx0p,           // [8][3072] packed ring, pre-zeroed
    ull* __restrict__ hx1p,           // [8][3072] packed ring, pre-zeroed
    _Float16* __restrict__ h1hist)    // (2048,768) fp16, row = t*4+b
{
  __shared__ __align__(16) float h0buf[G4];        // [k][b] (3 syncs -> single buffer safe)
  __shared__ __align__(16) float h1buf[G4];        // [k][b] (L1 carry)
  __shared__ __align__(16) float red[4][8][4][4];  // [gate][c][q][b]
  __shared__ float actv[4][8][4];                  // [gate][c][b]
  __shared__ float cst[8][4];

  const int t = threadIdx.x, lane = t & 63, wv = t >> 6;
  const bool L1 = blockIdx.x >= 96;
  const int lid = L1 ? (blockIdx.x - 96) : blockIdx.x;
  const int j0 = lid * 8;

  const float* WhhL = Whh + (L1 ? (size_t)G4 * H_SZ : 0);

  // W_hh fp32 slice (r12 shape): wreg[c][kk]
  float wreg[8][12];
#pragma unroll
  for (int c = 0; c < 8; ++c)
#pragma unroll
    for (int kk = 0; kk < 12; ++kk)
      wreg[c][kk] = WhhL[(size_t)(wv * H_SZ + j0 + c) * H_SZ + kk * 64 + lane];

  // L1: W_ih1 fp32 slice (r12 shape)
  float wreg2[8][12];
  if (L1) {
#pragma unroll
    for (int c = 0; c < 8; ++c)
#pragma unroll
      for (int kk = 0; kk < 12; ++kk)
        wreg2[c][kk] = Wih1[(size_t)(wv * H_SZ + j0 + c) * H_SZ + kk * 64 + lane];
  }

  const int g_ = t >> 5, c_ = (t >> 2) & 7, b_ = t & 3;

  float breg = 0.f;
  if (L1 && t < 128) breg = bias[G4 + g_ * H_SZ + j0 + c_];

  if (t < 32) cst[t >> 2][t & 3] = 0.f;

  const int elim = L1 ? 513 : 512;
  for (int e = 0; e < elim; ++e) {
    if (L1 && e == 0) {
      // seed h1[-1] = 0 with tag 1 into ring slot 0 (own cols)
      if (t < 32) {
        int c = t >> 2, b = t & 3;
        __hip_atomic_store(&hx1p[(size_t)(j0 + c) * 4 + b], (ull)1u << 32,
                           __ATOMIC_RELAXED, __HIP_MEMORY_SCOPE_AGENT);
      }
      continue;  // block-uniform: no LDS touched, barriers legally skipped
    }

    // L0 xg prefetch (independent of h) before polls
    float xgv = 0.f;
    if (!L1 && t < 128)
      xgv = xg0[(size_t)((e << 2) + b_) * G4 + g_ * H_SZ + j0 + c_];

    // L0 back-pressure (t0, e>=5): one h1 word, slot (e-5)&7, tag >= e-4
    if (!L1 && t == 0 && e >= 5) {
      const ull* bp = hx1p + (size_t)((e - 5) & 7) * G4;
      while ((unsigned)(__hip_atomic_load(bp, __ATOMIC_RELAXED, __HIP_MEMORY_SCOPE_AGENT) >> 32)
             < (unsigned)(e - 4))
        __builtin_amdgcn_s_sleep(1);
    }

    const unsigned need = (unsigned)e;

    // tag-gated gather h0[e-1] (ring slot (e-1)&7) into LDS (r12's 12-word shape)
    {
      const ull* s0 = hx0p + (size_t)((e + 7) & 7) * G4;
      ull v[12];
#pragma unroll
      for (int i = 0; i < 12; ++i)
        v[i] = __hip_atomic_load(&s0[t + i * 256], __ATOMIC_RELAXED, __HIP_MEMORY_SCOPE_AGENT);
      for (;;) {
        bool stale = false;
#pragma unroll
        for (int i = 0; i < 12; ++i) stale |= ((unsigned)(v[i] >> 32) < need);
        if (!stale) break;
        __builtin_amdgcn_s_sleep(1);
#pragma unroll
        for (int i = 0; i < 12; ++i)
          if ((unsigned)(v[i] >> 32) < need)
            v[i] = __hip_atomic_load(&s0[t + i * 256], __ATOMIC_RELAXED, __HIP_MEMORY_SCOPE_AGENT);
      }
#pragma unroll
      for (int i = 0; i < 12; ++i) h0buf[t + i * 256] = __uint_as_float((unsigned)v[i]);
    }
    // L1: tag-gated gather h1[e-2]-carry (ring slot (e-1)&7)
    if (L1) {
      const ull* s1 = hx1p + (size_t)((e + 7) & 7) * G4;
      ull v[12];
#pragma unroll
      for (int i = 0; i < 12; ++i)
        v[i] = __hip_atomic_load(&s1[t + i * 256], __ATOMIC_RELAXED, __HIP_MEMORY_SCOPE_AGENT);
      for (;;) {
        bool stale = false;
#pragma unroll
        for (int i = 0; i < 12; ++i) stale |= ((unsigned)(v[i] >> 32) < need);
        if (!stale) break;
        __builtin_amdgcn_s_sleep(1);
#pragma unroll
        for (int i = 0; i < 12; ++i)
          if ((unsigned)(v[i] >> 32) < need)
            v[i] = __hip_atomic_load(&s1[t + i * 256], __ATOMIC_RELAXED, __HIP_MEMORY_SCOPE_AGENT);
      }
#pragma unroll
      for (int i = 0; i < 12; ++i) h1buf[t + i * 256] = __uint_as_float((unsigned)v[i]);
    }
    __syncthreads();   // sync 1

    // matvec + butterfly (r12 shape)
    float4 acc[8];
#pragma unroll
    for (int c = 0; c < 8; ++c) acc[c] = make_float4(0.f, 0.f, 0.f, 0.f);

    if (!L1) {
#pragma unroll
      for (int kk = 0; kk < 12; ++kk) {
        float4 h4 = *(const float4*)&h0buf[(kk * 64 + lane) * 4];
#pragma unroll
        for (int c = 0; c < 8; ++c) {
          float wf = wreg[c][kk];
          acc[c].x = fmaf(wf, h4.x, acc[c].x);
          acc[c].y = fmaf(wf, h4.y, acc[c].y);
          acc[c].z = fmaf(wf, h4.z, acc[c].z);
          acc[c].w = fmaf(wf, h4.w, acc[c].w);
        }
      }
    } else {
#pragma unroll
      for (int kk = 0; kk < 12; ++kk) {
        float4 x4 = *(const float4*)&h0buf[(kk * 64 + lane) * 4];  // x = h0[e-1]
        float4 h4 = *(const float4*)&h1buf[(kk * 64 + lane) * 4];  // carry h1[e-2]
#pragma unroll
        for (int c = 0; c < 8; ++c) {
          float wx = wreg2[c][kk], wh = wreg[c][kk];
          acc[c].x = fmaf(wx, x4.x, fmaf(wh, h4.x, acc[c].x));
          acc[c].y = fmaf(wx, x4.y, fmaf(wh, h4.y, acc[c].y));
          acc[c].z = fmaf(wx, x4.z, fmaf(wh, h4.z, acc[c].z));
          acc[c].w = fmaf(wx, x4.w, fmaf(wh, h4.w, acc[c].w));
        }
      }
    }

#pragma unroll
    for (int mask = 1; mask <= 8; mask <<= 1) {
#pragma unroll
      for (int c = 0; c < 8; ++c) {
        acc[c].x += __shfl_xor(acc[c].x, mask, 64);
        acc[c].y += __shfl_xor(acc[c].y, mask, 64);
        acc[c].z += __shfl_xor(acc[c].z, mask, 64);
        acc[c].w += __shfl_xor(acc[c].w, mask, 64);
      }
    }
    if ((lane & 15) == 0) {
      int q = lane >> 4;
#pragma unroll
      for (int c = 0; c < 8; ++c) *(float4*)&red[wv][c][q][0] = acc[c];
    }
    __syncthreads();   // sync 2

    // activation (t<128)
    if (t < 128) {
      float s = red[g_][c_][0][b_] + red[g_][c_][1][b_] + red[g_][c_][2][b_] + red[g_][c_][3][b_]
              + (L1 ? breg : xgv);
      actv[g_][c_][b_] = (g_ == 2) ? tanhf(s) : (1.f / (1.f + expf(-s)));
    }
    __syncthreads();   // sync 3

    // combine + packed ring store (t<32); NO vmcnt, NO flag (tags only)
    if (t < 32) {
      int c = t >> 2, b = t & 3;
      float iv = actv[0][c][b], fv = actv[1][c][b], gv = actv[2][c][b], ov = actv[3][c][b];
      float cn = fv * cst[c][b] + iv * gv;
      cst[c][b] = cn;
      float hn = ov * tanhf(cn);
      ull p = ((ull)(unsigned)(e + 1) << 32) | (ull)__float_as_uint(hn);
      ull* dst = (L1 ? hx1p : hx0p) + (size_t)(e & 7) * G4;
      __hip_atomic_store(&dst[(size_t)(j0 + c) * 4 + b], p,
                         __ATOMIC_RELAXED, __HIP_MEMORY_SCOPE_AGENT);
      if (L1)
        h1hist[(size_t)(((e - 1) << 2) + b) * H_SZ + j0 + c] = (_Float16)hn;
    }
    // loop-top tag polls + sync1 order next epoch's LDS overwrites after
    // this epoch's reads (two syncs separate matvec reads from next gather).
  }
}

// ---------------- launcher ----------------

extern "C" void kernel_launch(void* const* d_in, const int* in_sizes, int n_in,
                              void* d_out, int out_size, void* d_ws, size_t ws_size,
                              hipStream_t stream) {
  const float* reps   = (const float*)d_in[0];
  const float* W_ih   = (const float*)d_in[1];
  const float* W_hh   = (const float*)d_in[2];
  const float* bias   = (const float*)d_in[3];
  const float* head_w = (const float*)d_in[4];
  const float* head_b = (const float*)d_in[5];
  float* out = (float*)d_out;

  char* ws = (char*)d_ws;
  _Float16* A0h    = (_Float16*)(ws + 0);            //  3,145,728 B
  _Float16* Wih_h  = (_Float16*)(ws + 3145728);      //  4,718,592 B (layer 0 only)
  _Float16* Whead  = (_Float16*)(ws + 12582912);     // 77,266,944 B (padded)
  float*    xg0    = (float*)   (ws + 89849856);     // 25,165,824 B
  _Float16* h1hist = (_Float16*)(ws + 115015680);    //  3,145,728 B
  ull*      hx0p   = (ull*)     (ws + 118161408);    //    196,608 B ([8][3072] packed)
  ull*      hx1p   = (ull*)     (ws + 118358016);    //    196,608 B ([8][3072] packed)

  // conversions
  hipLaunchKernelGGL(conv_A0,   dim3(1024), dim3(256), 0, stream, reps, A0h);
  hipLaunchKernelGGL(conv_cast, dim3(1024), dim3(256), 0, stream, W_ih, Wih_h, G4 * D_SZ);
  hipLaunchKernelGGL(conv_head, dim3(4096), dim3(256), 0, stream, head_w, Whead);

  // xg0 = A0 * Wih0^T + b0
  hipLaunchKernelGGL(gemm_bt_f16, dim3(16, 24), dim3(256), 0, stream,
                     A0h, Wih_h, bias, xg0, M_SZ, G4, H_SZ, 0, G4);

  // ring-tag pipelined 2-layer scan (192 blocks x 256 threads)
  hipMemsetAsync(hx0p, 0, 393216, stream);  // hx0p + hx1p contiguous
  hipLaunchKernelGGL(lstm_fused, dim3(FUSE_WGS), dim3(256), 0, stream,
                     xg0, W_ih + (size_t)G4 * D_SZ, W_hh, bias,
                     hx0p, hx1p, h1hist);

  // logits = h1 * head_w^T + head_b  (padded N, permuted store into (B,T,V))
  hipLaunchKernelGGL(gemm_bt_f16, dim3(16, 393), dim3(256), 0, stream,
                     h1hist, Whead, head_b, out, M_SZ, V_PAD, H_SZ, 1, V_SZ);
}

// Round 18
// 3008.578 us; speedup vs baseline: 8.3265x; 1.0027x over previous
//
#include <hip/hip_runtime.h>
#include <hip/hip_fp16.h>
#include <cstdint>

#define B_SZ 4
#define T_SZ 512
#define D_SZ 768
#define H_SZ 768
#define G4   3072           // 4*H
#define V_SZ 50257
#define V_PAD 50304         // 393*128
#define M_SZ 2048           // T*B
#define FUSE_WGS 192        // 96 L0 blocks + 96 L1 blocks, 256 threads each

using half8 = __attribute__((ext_vector_type(8))) _Float16;
using f32x4 = __attribute__((ext_vector_type(4))) float;
typedef unsigned long long ull;

// ---------------- conversion kernels ----------------

__global__ void conv_A0(const float* __restrict__ reps, _Float16* __restrict__ A0) {
  int idx = blockIdx.x * blockDim.x + threadIdx.x;
  const int total = M_SZ * D_SZ;
  for (; idx < total; idx += gridDim.x * blockDim.x) {
    int k = idx % D_SZ, m = idx / D_SZ;
    int t = m >> 2, b = m & 3;
    A0[idx] = (_Float16)reps[(b * T_SZ + t) * D_SZ + k];
  }
}

__global__ void conv_cast(const float* __restrict__ src, _Float16* __restrict__ dst, int n) {
  int idx = blockIdx.x * blockDim.x + threadIdx.x;
  for (; idx < n; idx += gridDim.x * blockDim.x) dst[idx] = (_Float16)src[idx];
}

__global__ void conv_head(const float* __restrict__ w, _Float16* __restrict__ dst) {
  int idx = blockIdx.x * blockDim.x + threadIdx.x;
  const int total = V_PAD * H_SZ;
  for (; idx < total; idx += gridDim.x * blockDim.x) {
    int n = idx / H_SZ, k = idx % H_SZ;
    dst[idx] = (n < V_SZ) ? (_Float16)w[n * H_SZ + k] : (_Float16)0.f;
  }
}

// ---------------- f16 MFMA GEMM: C[m][n] = sum_k A[m][k]*B[n][k] + bias[n] ----------------
// ROUND-18 CHANGE: staging via __builtin_amdgcn_global_load_lds width=16
// (m97-ladder-proven 1.4-1.7x on this exact 128^2/BK=32 structure). The
// original reg-staged layout was already linear (thread t -> LDS byte t*16),
// i.e. wave-uniform base + lane*16 -- the exact pattern the instruction
// requires -- so the swap is mechanical. Per wave w: dest = buf + w*1024B.

__global__ __launch_bounds__(256) void gemm_bt_f16(
    const _Float16* __restrict__ A, const _Float16* __restrict__ B,
    const float* __restrict__ bias, float* __restrict__ C,
    int M, int N, int K, int mode, int Nreal)
{
  __shared__ __align__(16) _Float16 As[128][32];
  __shared__ __align__(16) _Float16 Bs[128][32];
  const int t = threadIdx.x;
  const int lane = t & 63, w = t >> 6;
  const int wr = w >> 1, wc = w & 1;
  const int m0 = blockIdx.x * 128, n0 = blockIdx.y * 128;

  f32x4 acc[4][4] = {};

  const int srow = t >> 2;            // 0..63
  const int scol = (t & 3) * 8;       // halves within 32

  // per-lane global sources (linear-in-t LDS mapping preserved)
  const _Float16* ga0 = &A[(size_t)(m0 + srow) * K + scol];
  const _Float16* ga1 = &A[(size_t)(m0 + 64 + srow) * K + scol];
  const _Float16* gb0 = &B[(size_t)(n0 + srow) * K + scol];
  const _Float16* gb1 = &B[(size_t)(n0 + 64 + srow) * K + scol];
  // wave-uniform LDS dests (+ w*512 halves = w*1024 bytes)
  _Float16* lA0 = &As[0][0] + w * 512;
  _Float16* lA1 = &As[64][0] + w * 512;
  _Float16* lB0 = &Bs[0][0] + w * 512;
  _Float16* lB1 = &Bs[64][0] + w * 512;

  for (int k0 = 0; k0 < K; k0 += 32) {
    __syncthreads();                  // prior frag reads done; LDS overwritable
    __builtin_amdgcn_global_load_lds(ga0 + k0, lA0, 16, 0, 0);
    __builtin_amdgcn_global_load_lds(ga1 + k0, lA1, 16, 0, 0);
    __builtin_amdgcn_global_load_lds(gb0 + k0, lB0, 16, 0, 0);
    __builtin_amdgcn_global_load_lds(gb1 + k0, lB1, 16, 0, 0);
    asm volatile("s_waitcnt vmcnt(0)" ::: "memory");
    __syncthreads();

    const int fr = lane & 15, k8 = (lane >> 4) * 8;
    half8 af[4], bf[4];
#pragma unroll
    for (int i = 0; i < 4; ++i) {
      af[i] = *(const half8*)&As[wr * 64 + i * 16 + fr][k8];
      bf[i] = *(const half8*)&Bs[wc * 64 + i * 16 + fr][k8];
    }
#pragma unroll
    for (int i = 0; i < 4; ++i)
#pragma unroll
      for (int j = 0; j < 4; ++j)
        acc[i][j] = __builtin_amdgcn_mfma_f32_16x16x32_f16(af[i], bf[j], acc[i][j], 0, 0, 0);
  }

  const int fr = lane & 15, rq = lane >> 4;
#pragma unroll
  for (int i = 0; i < 4; ++i) {
#pragma unroll
    for (int j = 0; j < 4; ++j) {
      int n = n0 + wc * 64 + j * 16 + fr;
      if (n >= Nreal) continue;
      float bv = bias[n];
#pragma unroll
      for (int r = 0; r < 4; ++r) {
        int m = m0 + wr * 64 + i * 16 + rq * 4 + r;
        float v = acc[i][j][r] + bv;
        if (mode == 0) {
          C[(size_t)m * N + n] = v;
        } else {
          int tt = m >> 2, bb = m & 3;
          C[(size_t)(bb * T_SZ + tt) * V_SZ + n] = v;
        }
      }
    }
  }
}

// ---------------- round-16 scan (VERBATIM; proven 240 VGPR, no spill) ----------------
// r12 compute shape + r13 ring-tag sync. See r16 notes: ring[8] of
// [tag:u32|f32:u32] 8B relaxed agent atomics; store epoch e -> slot e&7 tag
// e+1; reader epoch x -> slot (x-1)&7 tag >= x. No flags, no vmcnt drain.
// L0 back-pressure (t0, e>=5): one hx1p word slot (e-5)&7 tag >= e-4 caps
// lead < 8 (transitive-tag safety). L1 e=0 seeds h1 slot 0 tag 1. r17's
// 3-group variant (288 blocks) hung -- first design needing 2-blocks/CU
// co-residency for a poll-coupled grid; reverted per zero-info-failure rule.

__global__ __launch_bounds__(256) void lstm_fused(
    const float* __restrict__ xg0,    // (2048,3072) layer-0 input projections
    const float* __restrict__ Wih1,   // (3072,768) fp32 layer-1 input weights
    const float* __restrict__ Whh,    // (2,3072,768) fp32
    const float* __restrict__ bias,   // (2,3072) fp32
    ull* __restrict__ hx0p,           // [8][3072] packed ring, pre-zeroed
    ull* __restrict__ hx1p,           // [8][3072] packed ring, pre-zeroed
    _Float16* __restrict__ h1hist)    // (2048,768) fp16, row = t*4+b
{
  __shared__ __align__(16) float h0buf[G4];        // [k][b]
  __shared__ __align__(16) float h1buf[G4];        // [k][b] (L1 carry)
  __shared__ __align__(16) float red[4][8][4][4];  // [gate][c][q][b]
  __shared__ float actv[4][8][4];                  // [gate][c][b]
  __shared__ float cst[8][4];

  const int t = threadIdx.x, lane = t & 63, wv = t >> 6;
  const bool L1 = blockIdx.x >= 96;
  const int lid = L1 ? (blockIdx.x - 96) : blockIdx.x;
  const int j0 = lid * 8;

  const float* WhhL = Whh + (L1 ? (size_t)G4 * H_SZ : 0);

  float wreg[8][12];
#pragma unroll
  for (int c = 0; c < 8; ++c)
#pragma unroll
    for (int kk = 0; kk < 12; ++kk)
      wreg[c][kk] = WhhL[(size_t)(wv * H_SZ + j0 + c) * H_SZ + kk * 64 + lane];

  float wreg2[8][12];
  if (L1) {
#pragma unroll
    for (int c = 0; c < 8; ++c)
#pragma unroll
      for (int kk = 0; kk < 12; ++kk)
        wreg2[c][kk] = Wih1[(size_t)(wv * H_SZ + j0 + c) * H_SZ + kk * 64 + lane];
  }

  const int g_ = t >> 5, c_ = (t >> 2) & 7, b_ = t & 3;

  float breg = 0.f;
  if (L1 && t < 128) breg = bias[G4 + g_ * H_SZ + j0 + c_];

  if (t < 32) cst[t >> 2][t & 3] = 0.f;

  const int elim = L1 ? 513 : 512;
  for (int e = 0; e < elim; ++e) {
    if (L1 && e == 0) {
      if (t < 32) {
        int c = t >> 2, b = t & 3;
        __hip_atomic_store(&hx1p[(size_t)(j0 + c) * 4 + b], (ull)1u << 32,
                           __ATOMIC_RELAXED, __HIP_MEMORY_SCOPE_AGENT);
      }
      continue;  // block-uniform: no LDS touched, barriers legally skipped
    }

    float xgv = 0.f;
    if (!L1 && t < 128)
      xgv = xg0[(size_t)((e << 2) + b_) * G4 + g_ * H_SZ + j0 + c_];

    if (!L1 && t == 0 && e >= 5) {
      const ull* bp = hx1p + (size_t)((e - 5) & 7) * G4;
      while ((unsigned)(__hip_atomic_load(bp, __ATOMIC_RELAXED, __HIP_MEMORY_SCOPE_AGENT) >> 32)
             < (unsigned)(e - 4))
        __builtin_amdgcn_s_sleep(1);
    }

    const unsigned need = (unsigned)e;

    {
      const ull* s0 = hx0p + (size_t)((e + 7) & 7) * G4;
      ull v[12];
#pragma unroll
      for (int i = 0; i < 12; ++i)
        v[i] = __hip_atomic_load(&s0[t + i * 256], __ATOMIC_RELAXED, __HIP_MEMORY_SCOPE_AGENT);
      for (;;) {
        bool stale = false;
#pragma unroll
        for (int i = 0; i < 12; ++i) stale |= ((unsigned)(v[i] >> 32) < need);
        if (!stale) break;
        __builtin_amdgcn_s_sleep(1);
#pragma unroll
        for (int i = 0; i < 12; ++i)
          if ((unsigned)(v[i] >> 32) < need)
            v[i] = __hip_atomic_load(&s0[t + i * 256], __ATOMIC_RELAXED, __HIP_MEMORY_SCOPE_AGENT);
      }
#pragma unroll
      for (int i = 0; i < 12; ++i) h0buf[t + i * 256] = __uint_as_float((unsigned)v[i]);
    }
    if (L1) {
      const ull* s1 = hx1p + (size_t)((e + 7) & 7) * G4;
      ull v[12];
#pragma unroll
      for (int i = 0; i < 12; ++i)
        v[i] = __hip_atomic_load(&s1[t + i * 256], __ATOMIC_RELAXED, __HIP_MEMORY_SCOPE_AGENT);
      for (;;) {
        bool stale = false;
#pragma unroll
        for (int i = 0; i < 12; ++i) stale |= ((unsigned)(v[i] >> 32) < need);
        if (!stale) break;
        __builtin_amdgcn_s_sleep(1);
#pragma unroll
        for (int i = 0; i < 12; ++i)
          if ((unsigned)(v[i] >> 32) < need)
            v[i] = __hip_atomic_load(&s1[t + i * 256], __ATOMIC_RELAXED, __HIP_MEMORY_SCOPE_AGENT);
      }
#pragma unroll
      for (int i = 0; i < 12; ++i) h1buf[t + i * 256] = __uint_as_float((unsigned)v[i]);
    }
    __syncthreads();   // sync 1

    float4 acc[8];
#pragma unroll
    for (int c = 0; c < 8; ++c) acc[c] = make_float4(0.f, 0.f, 0.f, 0.f);

    if (!L1) {
#pragma unroll
      for (int kk = 0; kk < 12; ++kk) {
        float4 h4 = *(const float4*)&h0buf[(kk * 64 + lane) * 4];
#pragma unroll
        for (int c = 0; c < 8; ++c) {
          float wf = wreg[c][kk];
          acc[c].x = fmaf(wf, h4.x, acc[c].x);
          acc[c].y = fmaf(wf, h4.y, acc[c].y);
          acc[c].z = fmaf(wf, h4.z, acc[c].z);
          acc[c].w = fmaf(wf, h4.w, acc[c].w);
        }
      }
    } else {
#pragma unroll
      for (int kk = 0; kk < 12; ++kk) {
        float4 x4 = *(const float4*)&h0buf[(kk * 64 + lane) * 4];
        float4 h4 = *(const float4*)&h1buf[(kk * 64 + lane) * 4];
#pragma unroll
        for (int c = 0; c < 8; ++c) {
          float wx = wreg2[c][kk], wh = wreg[c][kk];
          acc[c].x = fmaf(wx, x4.x, fmaf(wh, h4.x, acc[c].x));
          acc[c].y = fmaf(wx, x4.y, fmaf(wh, h4.y, acc[c].y));
          acc[c].z = fmaf(wx, x4.z, fmaf(wh, h4.z, acc[c].z));
          acc[c].w = fmaf(wx, x4.w, fmaf(wh, h4.w, acc[c].w));
        }
      }
    }

#pragma unroll
    for (int mask = 1; mask <= 8; mask <<= 1) {
#pragma unroll
      for (int c = 0; c < 8; ++c) {
        acc[c].x += __shfl_xor(acc[c].x, mask, 64);
        acc[c].y += __shfl_xor(acc[c].y, mask, 64);
        acc[c].z += __shfl_xor(acc[c].z, mask, 64);
        acc[c].w += __shfl_xor(acc[c].w, mask, 64);
      }
    }
    if ((lane & 15) == 0) {
      int q = lane >> 4;
#pragma unroll
      for (int c = 0; c < 8; ++c) *(float4*)&red[wv][c][q][0] = acc[c];
    }
    __syncthreads();   // sync 2

    if (t < 128) {
      float s = red[g_][c_][0][b_] + red[g_][c_][1][b_] + red[g_][c_][2][b_] + red[g_][c_][3][b_]
              + (L1 ? breg : xgv);
      actv[g_][c_][b_] = (g_ == 2) ? tanhf(s) : (1.f / (1.f + expf(-s)));
    }
    __syncthreads();   // sync 3

    if (t < 32) {
      int c = t >> 2, b = t & 3;
      float iv = actv[0][c][b], fv = actv[1][c][b], gv = actv[2][c][b], ov = actv[3][c][b];
      float cn = fv * cst[c][b] + iv * gv;
      cst[c][b] = cn;
      float hn = ov * tanhf(cn);
      ull p = ((ull)(unsigned)(e + 1) << 32) | (ull)__float_as_uint(hn);
      ull* dst = (L1 ? hx1p : hx0p) + (size_t)(e & 7) * G4;
      __hip_atomic_store(&dst[(size_t)(j0 + c) * 4 + b], p,
                         __ATOMIC_RELAXED, __HIP_MEMORY_SCOPE_AGENT);
      if (L1)
        h1hist[(size_t)(((e - 1) << 2) + b) * H_SZ + j0 + c] = (_Float16)hn;
    }
  }
}

// ---------------- launcher ----------------

extern "C" void kernel_launch(void* const* d_in, const int* in_sizes, int n_in,
                              void* d_out, int out_size, void* d_ws, size_t ws_size,
                              hipStream_t stream) {
  const float* reps   = (const float*)d_in[0];
  const float* W_ih   = (const float*)d_in[1];
  const float* W_hh   = (const float*)d_in[2];
  const float* bias   = (const float*)d_in[3];
  const float* head_w = (const float*)d_in[4];
  const float* head_b = (const float*)d_in[5];
  float* out = (float*)d_out;

  char* ws = (char*)d_ws;
  _Float16* A0h    = (_Float16*)(ws + 0);            //  3,145,728 B
  _Float16* Wih_h  = (_Float16*)(ws + 3145728);      //  4,718,592 B (layer 0 only)
  _Float16* Whead  = (_Float16*)(ws + 12582912);     // 77,266,944 B (padded)
  float*    xg0    = (float*)   (ws + 89849856);     // 25,165,824 B
  _Float16* h1hist = (_Float16*)(ws + 115015680);    //  3,145,728 B
  ull*      hx0p   = (ull*)     (ws + 118161408);    //    196,608 B ([8][3072] packed)
  ull*      hx1p   = (ull*)     (ws + 118358016);    //    196,608 B ([8][3072] packed)

  // conversions
  hipLaunchKernelGGL(conv_A0,   dim3(1024), dim3(256), 0, stream, reps, A0h);
  hipLaunchKernelGGL(conv_cast, dim3(1024), dim3(256), 0, stream, W_ih, Wih_h, G4 * D_SZ);
  hipLaunchKernelGGL(conv_head, dim3(4096), dim3(256), 0, stream, head_w, Whead);

  // xg0 = A0 * Wih0^T + b0
  hipLaunchKernelGGL(gemm_bt_f16, dim3(16, 24), dim3(256), 0, stream,
                     A0h, Wih_h, bias, xg0, M_SZ, G4, H_SZ, 0, G4);

  // ring-tag pipelined 2-layer scan (192 blocks x 256 threads)
  hipMemsetAsync(hx0p, 0, 393216, stream);  // hx0p + hx1p contiguous
  hipLaunchKernelGGL(lstm_fused, dim3(FUSE_WGS), dim3(256), 0, stream,
                     xg0, W_ih + (size_t)G4 * D_SZ, W_hh, bias,
                     hx0p, hx1p, h1hist);

  // logits = h1 * head_w^T + head_b  (padded N, permuted store into (B,T,V))
  hipLaunchKernelGGL(gemm_bt_f16, dim3(16, 393), dim3(256), 0, stream,
                     h1hist, Whead, head_b, out, M_SZ, V_PAD, H_SZ, 1, V_SZ);
}